// Round 3
// baseline (3431.350 us; speedup 1.0000x reference)
//
#include <hip/hip_runtime.h>
#include <math.h>

#define Bsz 8
#define Dd  128
#define Tt  4096
#define Kk  1024
#define NQ  8
#define BT  (Bsz*Tt)        // 32768 points
#define KG  4               // K-groups (code-split across blocks)
#define CPG (Kk/KG)         // 256 codes per K-group (64 per wave)
#define PTS 128             // points per argmin block

// ---------------------------------------------------------------------------
// init: transpose x (B,D,T) -> resid (B,T,D)
// ---------------------------------------------------------------------------
__global__ void k_init(const float* __restrict__ x,
                       float* __restrict__ resid) {
    __shared__ float tile[32][33];
    int b  = blockIdx.z;
    int t0 = blockIdx.x * 32, d0 = blockIdx.y * 32;
    int tx = threadIdx.x, ty = threadIdx.y;   // 32 x 8
    #pragma unroll
    for (int k = 0; k < 4; k++) {
        int d = d0 + ty + k * 8;
        tile[ty + k * 8][tx] = x[((size_t)(b * Dd + d)) * Tt + t0 + tx];
    }
    __syncthreads();
    #pragma unroll
    for (int k = 0; k < 4; k++) {
        int t = t0 + ty + k * 8;
        resid[((size_t)(b * Tt + t)) * Dd + d0 + tx] = tile[tx][ty + k * 8];
    }
}

// ---------------------------------------------------------------------------
// c2[q][k] = sum_d cb[q][k][d]^2 ; zero commit accumulators
// ---------------------------------------------------------------------------
__global__ void k_c2(const float* __restrict__ cb,
                     float* __restrict__ c2,
                     double* __restrict__ commits) {
    int row  = blockIdx.x * 4 + (threadIdx.x >> 6);
    int lane = threadIdx.x & 63;
    const float* p = cb + (size_t)row * Dd;
    float a = p[lane], b = p[lane + 64];
    float s = a * a + b * b;
    #pragma unroll
    for (int off = 32; off; off >>= 1) s += __shfl_down(s, off);
    if (lane == 0) c2[row] = s;
    if (blockIdx.x == 0 && threadIdx.x < NQ) commits[threadIdx.x] = 0.0;
}

// ---------------------------------------------------------------------------
// argmin, codes-in-lanes: each lane holds ONE code vector in 32 float4 VGPRs;
// point data streams through the scalar pipe (wave-uniform address -> s_load
// broadcast). No LDS / no barriers in the hot loop. Per block: 4 waves cover
// 256 codes (one K-group), 128 points.
// Tie-break = first occurrence: lane-ascending codes -> ffs(ballot(==min));
// wave combine uses strict < over ascending code ranges.
// ---------------------------------------------------------------------------
__global__ __launch_bounds__(256, 3) void k_argmin_sgpr(
        const float* __restrict__ resid,
        const float* __restrict__ cb,     // this stage's (K x D) codebook
        const float* __restrict__ c2,     // this stage's c2 (K)
        float* __restrict__ pval,         // (BT, KG)
        int*   __restrict__ pidx) {
    __shared__ float redv[KG][PTS];
    __shared__ int   redi[KG][PTS];

    int tid  = threadIdx.x;
    int w    = tid >> 6;                    // wave 0..3
    int lane = tid & 63;
    int kg   = blockIdx.x & (KG - 1);
    int base = (blockIdx.x >> 2) * PTS;     // first point of this block
    int code = kg * CPG + w * 64 + lane;    // this lane's code

    // preamble: lane's code vector -> registers (L2-resident codebook)
    float4 cd[32];
    const float4* cp = (const float4*)(cb + (size_t)code * Dd);
    #pragma unroll
    for (int d = 0; d < 32; d++) cd[d] = cp[d];
    float myc2 = c2[code];

    const float4* rp = (const float4*)(resid + (size_t)base * Dd);

    for (int p = 0; p < PTS; p++) {
        const float4* r = rp + (size_t)p * 32;   // wave-uniform address
        float a0 = 0.f, a1 = 0.f, a2 = 0.f, a3 = 0.f;
        #pragma unroll
        for (int d = 0; d < 32; d++) {
            float4 s = r[d];                     // uniform -> s_load broadcast
            a0 = fmaf(s.x, cd[d].x, a0);
            a1 = fmaf(s.y, cd[d].y, a1);
            a2 = fmaf(s.z, cd[d].z, a2);
            a3 = fmaf(s.w, cd[d].w, a3);
        }
        float dot   = (a0 + a1) + (a2 + a3);
        float score = fmaf(-2.0f, dot, myc2);    // ||r||^2 const: argmin-inv.
        // wave-wide min, then first lane equal to it (first occurrence)
        float m = score;
        #pragma unroll
        for (int off = 32; off; off >>= 1) m = fminf(m, __shfl_xor(m, off));
        unsigned long long msk = __ballot(score == m);
        int fl = __ffsll((unsigned long long)msk) - 1;
        if (lane == 0) { redv[w][p] = m; redi[w][p] = kg * CPG + w * 64 + fl; }
    }
    __syncthreads();
    // combine the block's 4 waves (ascending code ranges -> strict <)
    for (int p = tid; p < PTS; p += 256) {
        float bv = redv[0][p]; int bi = redi[0][p];
        #pragma unroll
        for (int w2 = 1; w2 < KG; w2++) {
            float v = redv[w2][p];
            if (v < bv) { bv = v; bi = redi[w2][p]; }
        }
        pval[(size_t)(base + p) * KG + kg] = bv;
        pidx[(size_t)(base + p) * KG + kg] = bi;
    }
}

// ---------------------------------------------------------------------------
// combine partials + residual STE update + commit partial. 16 points/block.
// K-groups are ascending code ranges -> strict < keeps first occurrence.
// ---------------------------------------------------------------------------
__global__ __launch_bounds__(256) void k_combine_update(
        float* __restrict__ resid,
        const float* __restrict__ cb,     // this stage's (K x D) codebook
        const float* __restrict__ pval,
        const int*   __restrict__ pidx,
        float* __restrict__ codes_f,      // already offset by q*BT
        double* __restrict__ commit) {
    __shared__ int   sidx[16];
    __shared__ float wsum[4];
    int tid  = threadIdx.x;
    int base = blockIdx.x * 16;

    if (tid < 16) {
        int p = base + tid;
        const float* pv = pval + (size_t)p * KG;
        const int*   pi = pidx + (size_t)p * KG;
        float bv = pv[0]; int bi = pi[0];
        #pragma unroll
        for (int h = 1; h < KG; h++) {
            float v = pv[h];
            if (v < bv) { bv = v; bi = pi[h]; }
        }
        sidx[tid]  = bi;
        codes_f[p] = (float)bi;
    }
    __syncthreads();

    int d = tid & 127, po = tid >> 7;
    float cacc = 0.0f;
    #pragma unroll
    for (int it = 0; it < 8; it++) {
        int p = it * 2 + po;
        size_t g = (size_t)(base + p) * Dd + d;
        float r  = resid[g];
        float qv = cb[(size_t)sidx[p] * Dd + d];
        float t1  = qv - r;       // q - residual
        float qst = r + t1;       // straight-through value
        resid[g]  = r - qst;      // next residual
        cacc += t1 * t1;
    }
    #pragma unroll
    for (int off = 32; off; off >>= 1) cacc += __shfl_down(cacc, off);
    int lane = tid & 63, wv = tid >> 6;
    if (lane == 0) wsum[wv] = cacc;
    __syncthreads();
    if (tid == 0)
        atomicAdd(commit, (double)(wsum[0] + wsum[1] + wsum[2] + wsum[3]));
}

// ---------------------------------------------------------------------------
// final: out(B,D,T) = x - resid_final^T
// ---------------------------------------------------------------------------
__global__ void k_final(const float* __restrict__ x,
                        const float* __restrict__ resid,
                        float* __restrict__ outq) {
    __shared__ float tile[32][33];
    int b  = blockIdx.z;
    int t0 = blockIdx.x * 32, d0 = blockIdx.y * 32;
    int tx = threadIdx.x, ty = threadIdx.y;   // 32 x 8
    #pragma unroll
    for (int k = 0; k < 4; k++) {
        int t = t0 + ty + k * 8;
        tile[ty + k * 8][tx] = resid[((size_t)(b * Tt + t)) * Dd + d0 + tx];
    }
    __syncthreads();
    #pragma unroll
    for (int k = 0; k < 4; k++) {
        int d = d0 + ty + k * 8;
        size_t o = ((size_t)(b * Dd + d)) * Tt + t0 + tx;
        outq[o] = x[o] - tile[tx][ty + k * 8];
    }
}

// ---------------------------------------------------------------------------
// scalars
// ---------------------------------------------------------------------------
__global__ void k_scalars(const double* __restrict__ commits,
                          const int* __restrict__ frame_rate,
                          float* __restrict__ outs) {
    if (threadIdx.x == 0 && blockIdx.x == 0) {
        double s = 0.0;
        #pragma unroll
        for (int q = 0; q < NQ; q++) s += commits[q];
        double per_elem = s / ((double)NQ * (double)BT * (double)Dd);
        outs[0] = (float)(NQ * 10.0 * (double)frame_rate[0]); // log2(1024)=10
        outs[1] = (float)per_elem;
    }
}

extern "C" void kernel_launch(void* const* d_in, const int* in_sizes, int n_in,
                              void* d_out, int out_size, void* d_ws, size_t ws_size,
                              hipStream_t stream) {
    const float* x  = (const float*)d_in[0];   // (B, D, T)
    const float* cb = (const float*)d_in[1];   // (NQ, K, D)
    const int*   fr = (const int*)d_in[2];     // frame_rate

    float* outq    = (float*)d_out;                       // (B,D,T) 4194304
    float* codes_f = outq + (size_t)Bsz * Dd * Tt;        // (NQ,B,T) 262144
    float* scal    = codes_f + (size_t)NQ * BT;           // bw, penalty

    char* ws = (char*)d_ws;
    float*  resid   = (float*)ws;                             // BT*D
    float*  c2      = resid + (size_t)BT * Dd;                // NQ*K
    float*  pval    = c2 + (size_t)NQ * Kk;                   // BT*KG
    int*    pidx    = (int*)(pval + (size_t)BT * KG);         // BT*KG
    double* commits = (double*)(pidx + (size_t)BT * KG);      // NQ

    dim3 tb(32, 8, 1);
    k_init<<<dim3(Tt / 32, Dd / 32, Bsz), tb, 0, stream>>>(x, resid);
    k_c2<<<NQ * Kk / 4, 256, 0, stream>>>(cb, c2, commits);

    for (int q = 0; q < NQ; q++) {
        k_argmin_sgpr<<<(BT / PTS) * KG, 256, 0, stream>>>(
            resid, cb + (size_t)q * Kk * Dd, c2 + (size_t)q * Kk, pval, pidx);
        k_combine_update<<<BT / 16, 256, 0, stream>>>(
            resid, cb + (size_t)q * Kk * Dd, pval, pidx,
            codes_f + (size_t)q * BT, commits + q);
    }

    k_final<<<dim3(Tt / 32, Dd / 32, Bsz), tb, 0, stream>>>(x, resid, outq);
    k_scalars<<<1, 64, 0, stream>>>(commits, fr, scal);
}

// Round 4
// 1493.768 us; speedup vs baseline: 2.2971x; 2.2971x over previous
//
#include <hip/hip_runtime.h>
#include <math.h>

#define Bsz 8
#define Dd  128
#define Tt  4096
#define Kk  1024
#define NQ  8
#define BT  (Bsz*Tt)        // 32768 points
#define PW  16              // points per wave/block
#define NCH 4               // code chunks (4 * 256 = 1024)

// ---------------------------------------------------------------------------
// init: transpose x (B,D,T) -> resid (B,T,D)
// ---------------------------------------------------------------------------
__global__ void k_init(const float* __restrict__ x,
                       float* __restrict__ resid) {
    __shared__ float tile[32][33];
    int b  = blockIdx.z;
    int t0 = blockIdx.x * 32, d0 = blockIdx.y * 32;
    int tx = threadIdx.x, ty = threadIdx.y;   // 32 x 8
    #pragma unroll
    for (int k = 0; k < 4; k++) {
        int d = d0 + ty + k * 8;
        tile[ty + k * 8][tx] = x[((size_t)(b * Dd + d)) * Tt + t0 + tx];
    }
    __syncthreads();
    #pragma unroll
    for (int k = 0; k < 4; k++) {
        int t = t0 + ty + k * 8;
        resid[((size_t)(b * Tt + t)) * Dd + d0 + tx] = tile[tx][ty + k * 8];
    }
}

// ---------------------------------------------------------------------------
// cbT[q][d][k] = cb[q][k][d]  (once; reused by all stages)
// ---------------------------------------------------------------------------
__global__ void k_cbT(const float* __restrict__ cb, float* __restrict__ cbT) {
    __shared__ float tile[32][33];
    int q  = blockIdx.z;
    int k0 = blockIdx.x * 32, d0 = blockIdx.y * 32;
    int tx = threadIdx.x, ty = threadIdx.y;   // 32 x 8
    const float* src = cb  + (size_t)q * Kk * Dd;
    float*       dst = cbT + (size_t)q * Dd * Kk;
    #pragma unroll
    for (int r = 0; r < 4; r++) {
        int k = k0 + ty + r * 8;
        tile[ty + r * 8][tx] = src[(size_t)k * Dd + d0 + tx];
    }
    __syncthreads();
    #pragma unroll
    for (int r = 0; r < 4; r++) {
        int d = d0 + ty + r * 8;
        dst[(size_t)d * Kk + k0 + tx] = tile[tx][ty + r * 8];
    }
}

// ---------------------------------------------------------------------------
// c2[q][k] = sum_d cb[q][k][d]^2 ; zero commit accumulators
// ---------------------------------------------------------------------------
__global__ void k_c2(const float* __restrict__ cb,
                     float* __restrict__ c2,
                     double* __restrict__ commits) {
    int row  = blockIdx.x * 4 + (threadIdx.x >> 6);
    int lane = threadIdx.x & 63;
    const float* p = cb + (size_t)row * Dd;
    float a = p[lane], b = p[lane + 64];
    float s = a * a + b * b;
    #pragma unroll
    for (int off = 32; off; off >>= 1) s += __shfl_down(s, off);
    if (lane == 0) c2[row] = s;
    if (blockIdx.x == 0 && threadIdx.x < NQ) commits[threadIdx.x] = 0.0;
}

// ---------------------------------------------------------------------------
// Fused argmin + STE update. One wave per block: 16 points x 1024 codes.
// Lane owns 4 codes per chunk (acc = float4 acc[16] -> 64 VGPR, persistent).
// Point tile in LDS, read by same-address broadcast ds_read_b128 (free).
// Codebook columns stream coalesced from L2 (cbT[d][k]). No barriers in the
// hot loop. First-occurrence argmin: lane codes ascending in lane, chunks
// ascending, strict < per-lane; cross-lane tie -> smaller code.
// ---------------------------------------------------------------------------
__global__ __launch_bounds__(64, 2) void k_argmin_fused(
        float* resid,
        const float* __restrict__ cbT,    // (D x K) this stage
        const float* __restrict__ cb,     // (K x D) this stage
        const float* __restrict__ c2,     // (K)     this stage
        float* __restrict__ codes_f,      // offset by q*BT
        double* __restrict__ commit) {
    __shared__ float Rt[PW][132];         // 8448 B, row stride 528 B (16B-align)

    int lane = threadIdx.x;
    int base = blockIdx.x * PW;

    // stage 16 pts x 128 dims (coalesced global, 2-way-max LDS banks)
    #pragma unroll
    for (int j = 0; j < 8; j++) {
        int f = lane + 64 * j;            // 512 float4s total
        int p = f >> 5, d4 = f & 31;
        float4 v = *(const float4*)&resid[(size_t)(base + p) * Dd + d4 * 4];
        *(float4*)&Rt[p][d4 * 4] = v;
    }
    __syncthreads();

    float best[PW]; int bidx[PW];
    #pragma unroll
    for (int p = 0; p < PW; p++) { best[p] = INFINITY; bidx[p] = 0; }

    for (int ch = 0; ch < NCH; ch++) {
        int cbase = ch * 256 + lane * 4;  // this lane's 4 codes this chunk
        float4 acc[PW];
        #pragma unroll
        for (int p = 0; p < PW; p++) acc[p] = make_float4(0.f, 0.f, 0.f, 0.f);

        for (int k4 = 0; k4 < 32; k4++) { // 4 dims per iteration
            const float* col = cbT + (size_t)(k4 * 4) * Kk + cbase;
            float4 cv0 = *(const float4*)(col);
            float4 cv1 = *(const float4*)(col + Kk);
            float4 cv2 = *(const float4*)(col + 2 * Kk);
            float4 cv3 = *(const float4*)(col + 3 * Kk);
            #pragma unroll
            for (int p = 0; p < PW; p++) {
                float4 rv = *(const float4*)&Rt[p][k4 * 4];  // broadcast read
                acc[p].x = fmaf(rv.x, cv0.x, acc[p].x);
                acc[p].y = fmaf(rv.x, cv0.y, acc[p].y);
                acc[p].z = fmaf(rv.x, cv0.z, acc[p].z);
                acc[p].w = fmaf(rv.x, cv0.w, acc[p].w);
                acc[p].x = fmaf(rv.y, cv1.x, acc[p].x);
                acc[p].y = fmaf(rv.y, cv1.y, acc[p].y);
                acc[p].z = fmaf(rv.y, cv1.z, acc[p].z);
                acc[p].w = fmaf(rv.y, cv1.w, acc[p].w);
                acc[p].x = fmaf(rv.z, cv2.x, acc[p].x);
                acc[p].y = fmaf(rv.z, cv2.y, acc[p].y);
                acc[p].z = fmaf(rv.z, cv2.z, acc[p].z);
                acc[p].w = fmaf(rv.z, cv2.w, acc[p].w);
                acc[p].x = fmaf(rv.w, cv3.x, acc[p].x);
                acc[p].y = fmaf(rv.w, cv3.y, acc[p].y);
                acc[p].z = fmaf(rv.w, cv3.z, acc[p].z);
                acc[p].w = fmaf(rv.w, cv3.w, acc[p].w);
            }
        }

        // chunk epilogue: score = c2 - 2*dot; ascending cc, strict <
        float4 cc2 = *(const float4*)&c2[cbase];
        #pragma unroll
        for (int p = 0; p < PW; p++) {
            float s0 = fmaf(-2.0f, acc[p].x, cc2.x);
            float s1 = fmaf(-2.0f, acc[p].y, cc2.y);
            float s2 = fmaf(-2.0f, acc[p].z, cc2.z);
            float s3 = fmaf(-2.0f, acc[p].w, cc2.w);
            float v = s0; int ci = 0;
            if (s1 < v) { v = s1; ci = 1; }
            if (s2 < v) { v = s2; ci = 2; }
            if (s3 < v) { v = s3; ci = 3; }
            if (v < best[p]) { best[p] = v; bidx[p] = cbase + ci; }
        }
    }

    // cross-lane argmin per point (butterfly; all lanes converge), then
    // fused STE update: lane handles dims {2*lane, 2*lane+1}.
    int idxs[PW];
    #pragma unroll
    for (int p = 0; p < PW; p++) {
        float v = best[p]; int i = bidx[p];
        #pragma unroll
        for (int off = 32; off; off >>= 1) {
            float v2 = __shfl_xor(v, off);
            int   i2 = __shfl_xor(i, off);
            if (v2 < v || (v2 == v && i2 < i)) { v = v2; i = i2; }
        }
        idxs[p] = i;
        if (lane == p) codes_f[base + p] = (float)i;
    }

    float cacc = 0.0f;
    #pragma unroll
    for (int p = 0; p < PW; p++) {
        float2 q = *(const float2*)&cb[(size_t)idxs[p] * Dd + 2 * lane];
        float2 r = *(const float2*)&Rt[p][2 * lane];
        float t1x = q.x - r.x,  t1y = q.y - r.y;    // q - residual
        float qsx = r.x + t1x,  qsy = r.y + t1y;    // straight-through value
        float2 nr = make_float2(r.x - qsx, r.y - qsy);
        *(float2*)&resid[(size_t)(base + p) * Dd + 2 * lane] = nr;
        cacc = fmaf(t1x, t1x, cacc);
        cacc = fmaf(t1y, t1y, cacc);
    }
    #pragma unroll
    for (int off = 32; off; off >>= 1) cacc += __shfl_down(cacc, off);
    if (lane == 0) atomicAdd(commit, (double)cacc);
}

// ---------------------------------------------------------------------------
// final: out(B,D,T) = x - resid_final^T
// ---------------------------------------------------------------------------
__global__ void k_final(const float* __restrict__ x,
                        const float* __restrict__ resid,
                        float* __restrict__ outq) {
    __shared__ float tile[32][33];
    int b  = blockIdx.z;
    int t0 = blockIdx.x * 32, d0 = blockIdx.y * 32;
    int tx = threadIdx.x, ty = threadIdx.y;   // 32 x 8
    #pragma unroll
    for (int k = 0; k < 4; k++) {
        int t = t0 + ty + k * 8;
        tile[ty + k * 8][tx] = resid[((size_t)(b * Tt + t)) * Dd + d0 + tx];
    }
    __syncthreads();
    #pragma unroll
    for (int k = 0; k < 4; k++) {
        int d = d0 + ty + k * 8;
        size_t o = ((size_t)(b * Dd + d)) * Tt + t0 + tx;
        outq[o] = x[o] - tile[tx][ty + k * 8];
    }
}

// ---------------------------------------------------------------------------
// scalars: bw = n_q * log2(K) * frame_rate ; penalty = mean(commits)
// ---------------------------------------------------------------------------
__global__ void k_scalars(const double* __restrict__ commits,
                          const int* __restrict__ frame_rate,
                          float* __restrict__ outs) {
    if (threadIdx.x == 0 && blockIdx.x == 0) {
        double s = 0.0;
        #pragma unroll
        for (int q = 0; q < NQ; q++) s += commits[q];
        double per_elem = s / ((double)NQ * (double)BT * (double)Dd);
        outs[0] = (float)(NQ * 10.0 * (double)frame_rate[0]); // log2(1024)=10
        outs[1] = (float)per_elem;
    }
}

extern "C" void kernel_launch(void* const* d_in, const int* in_sizes, int n_in,
                              void* d_out, int out_size, void* d_ws, size_t ws_size,
                              hipStream_t stream) {
    const float* x  = (const float*)d_in[0];   // (B, D, T)
    const float* cb = (const float*)d_in[1];   // (NQ, K, D)
    const int*   fr = (const int*)d_in[2];     // frame_rate

    float* outq    = (float*)d_out;                       // (B,D,T) 4194304
    float* codes_f = outq + (size_t)Bsz * Dd * Tt;        // (NQ,B,T) 262144
    float* scal    = codes_f + (size_t)NQ * BT;           // bw, penalty

    char* ws = (char*)d_ws;
    float*  resid   = (float*)ws;                         // BT*D
    float*  cbT     = resid + (size_t)BT * Dd;            // NQ*D*K
    float*  c2      = cbT + (size_t)NQ * Dd * Kk;         // NQ*K
    double* commits = (double*)(c2 + (size_t)NQ * Kk);    // NQ

    dim3 tb(32, 8, 1);
    k_init<<<dim3(Tt / 32, Dd / 32, Bsz), tb, 0, stream>>>(x, resid);
    k_cbT<<<dim3(Kk / 32, Dd / 32, NQ), tb, 0, stream>>>(cb, cbT);
    k_c2<<<NQ * Kk / 4, 256, 0, stream>>>(cb, c2, commits);

    for (int q = 0; q < NQ; q++) {
        k_argmin_fused<<<BT / PW, 64, 0, stream>>>(
            resid,
            cbT + (size_t)q * Dd * Kk,
            cb  + (size_t)q * Kk * Dd,
            c2  + (size_t)q * Kk,
            codes_f + (size_t)q * BT,
            commits + q);
    }

    k_final<<<dim3(Tt / 32, Dd / 32, Bsz), tb, 0, stream>>>(x, resid, outq);
    k_scalars<<<1, 64, 0, stream>>>(commits, fr, scal);
}

// Round 5
// 1143.301 us; speedup vs baseline: 3.0013x; 1.3065x over previous
//
#include <hip/hip_runtime.h>
#include <math.h>

#define Bsz 8
#define Dd  128
#define Tt  4096
#define Kk  1024
#define NQ  8
#define BT  (Bsz*Tt)        // 32768 points
#define PW  8               // points per wave/block
#define CPL 8               // codes per lane
#define NCH 2               // chunks: 1024 / (64 lanes * CPL)

// ---------------------------------------------------------------------------
// init: transpose x (B,D,T) -> resid (B,T,D)
// ---------------------------------------------------------------------------
__global__ void k_init(const float* __restrict__ x,
                       float* __restrict__ resid) {
    __shared__ float tile[32][33];
    int b  = blockIdx.z;
    int t0 = blockIdx.x * 32, d0 = blockIdx.y * 32;
    int tx = threadIdx.x, ty = threadIdx.y;   // 32 x 8
    #pragma unroll
    for (int k = 0; k < 4; k++) {
        int d = d0 + ty + k * 8;
        tile[ty + k * 8][tx] = x[((size_t)(b * Dd + d)) * Tt + t0 + tx];
    }
    __syncthreads();
    #pragma unroll
    for (int k = 0; k < 4; k++) {
        int t = t0 + ty + k * 8;
        resid[((size_t)(b * Tt + t)) * Dd + d0 + tx] = tile[tx][ty + k * 8];
    }
}

// ---------------------------------------------------------------------------
// cbT[q][d][k] = cb[q][k][d]  (once; reused by all stages)
// ---------------------------------------------------------------------------
__global__ void k_cbT(const float* __restrict__ cb, float* __restrict__ cbT) {
    __shared__ float tile[32][33];
    int q  = blockIdx.z;
    int k0 = blockIdx.x * 32, d0 = blockIdx.y * 32;
    int tx = threadIdx.x, ty = threadIdx.y;   // 32 x 8
    const float* src = cb  + (size_t)q * Kk * Dd;
    float*       dst = cbT + (size_t)q * Dd * Kk;
    #pragma unroll
    for (int r = 0; r < 4; r++) {
        int k = k0 + ty + r * 8;
        tile[ty + r * 8][tx] = src[(size_t)k * Dd + d0 + tx];
    }
    __syncthreads();
    #pragma unroll
    for (int r = 0; r < 4; r++) {
        int d = d0 + ty + r * 8;
        dst[(size_t)d * Kk + k0 + tx] = tile[tx][ty + r * 8];
    }
}

// ---------------------------------------------------------------------------
// c2[q][k] = sum_d cb[q][k][d]^2 ; zero commit accumulators
// ---------------------------------------------------------------------------
__global__ void k_c2(const float* __restrict__ cb,
                     float* __restrict__ c2,
                     double* __restrict__ commits) {
    int row  = blockIdx.x * 4 + (threadIdx.x >> 6);
    int lane = threadIdx.x & 63;
    const float* p = cb + (size_t)row * Dd;
    float a = p[lane], b = p[lane + 64];
    float s = a * a + b * b;
    #pragma unroll
    for (int off = 32; off; off >>= 1) s += __shfl_down(s, off);
    if (lane == 0) c2[row] = s;
    if (blockIdx.x == 0 && threadIdx.x < NQ) commits[threadIdx.x] = 0.0;
}

// ---------------------------------------------------------------------------
// Fused argmin + STE update. One wave per block: 8 points x 1024 codes.
// Lane owns 8 codes per chunk (2 chunks). acc[8 pts][8 codes] = 64 VGPR.
// Total live in k-loop ~120 VGPR -> fits the 128 cap of (64,4) => 4 waves/SIMD
// (grid 4096 blocks / 1024 SIMDs). Point tile broadcast via ds_read_b64.
// Codebook columns stream coalesced from L2 (cbT[d][k]). No barriers in the
// hot loop. First-occurrence argmin: codes ascending in (chunk, lane, c),
// strict < everywhere; cross-lane tie -> smaller code.
// ---------------------------------------------------------------------------
__global__ __launch_bounds__(64, 4) void k_argmin_fused(
        float* resid,
        const float* __restrict__ cbT,    // (D x K) this stage
        const float* __restrict__ cb,     // (K x D) this stage
        const float* __restrict__ c2,     // (K)     this stage
        float* __restrict__ codes_f,      // offset by q*BT
        double* __restrict__ commit) {
    __shared__ float Rt[PW][132];         // 4224 B, row stride 528 B

    int lane = threadIdx.x;
    int base = blockIdx.x * PW;

    // stage 8 pts x 128 dims = 256 float4 (coalesced; 2-way-max LDS banks)
    #pragma unroll
    for (int j = 0; j < 4; j++) {
        int f = lane + 64 * j;
        int p = f >> 5, d4 = f & 31;
        float4 v = *(const float4*)&resid[(size_t)(base + p) * Dd + d4 * 4];
        *(float4*)&Rt[p][d4 * 4] = v;
    }
    __syncthreads();

    float best[PW]; int bidx[PW];
    #pragma unroll
    for (int p = 0; p < PW; p++) { best[p] = INFINITY; bidx[p] = 0; }

    for (int ch = 0; ch < NCH; ch++) {
        int cbase = ch * 512 + lane * CPL;   // this lane's 8 codes this chunk
        float acc[PW][CPL];
        #pragma unroll
        for (int p = 0; p < PW; p++)
            #pragma unroll
            for (int c = 0; c < CPL; c++) acc[p][c] = 0.0f;

        for (int k2 = 0; k2 < 64; k2++) {    // 2 dims per iteration
            const float* col = cbT + (size_t)(k2 * 2) * Kk + cbase;
            float4 cv0a = *(const float4*)(col);
            float4 cv0b = *(const float4*)(col + 4);
            float4 cv1a = *(const float4*)(col + Kk);
            float4 cv1b = *(const float4*)(col + Kk + 4);
            float2 rv[PW];
            #pragma unroll
            for (int p = 0; p < PW; p++)
                rv[p] = *(const float2*)&Rt[p][k2 * 2];   // broadcast b64
            #pragma unroll
            for (int p = 0; p < PW; p++) {
                acc[p][0] = fmaf(rv[p].x, cv0a.x, acc[p][0]);
                acc[p][1] = fmaf(rv[p].x, cv0a.y, acc[p][1]);
                acc[p][2] = fmaf(rv[p].x, cv0a.z, acc[p][2]);
                acc[p][3] = fmaf(rv[p].x, cv0a.w, acc[p][3]);
                acc[p][4] = fmaf(rv[p].x, cv0b.x, acc[p][4]);
                acc[p][5] = fmaf(rv[p].x, cv0b.y, acc[p][5]);
                acc[p][6] = fmaf(rv[p].x, cv0b.z, acc[p][6]);
                acc[p][7] = fmaf(rv[p].x, cv0b.w, acc[p][7]);
                acc[p][0] = fmaf(rv[p].y, cv1a.x, acc[p][0]);
                acc[p][1] = fmaf(rv[p].y, cv1a.y, acc[p][1]);
                acc[p][2] = fmaf(rv[p].y, cv1a.z, acc[p][2]);
                acc[p][3] = fmaf(rv[p].y, cv1a.w, acc[p][3]);
                acc[p][4] = fmaf(rv[p].y, cv1b.x, acc[p][4]);
                acc[p][5] = fmaf(rv[p].y, cv1b.y, acc[p][5]);
                acc[p][6] = fmaf(rv[p].y, cv1b.z, acc[p][6]);
                acc[p][7] = fmaf(rv[p].y, cv1b.w, acc[p][7]);
            }
        }

        // chunk epilogue: score = c2 - 2*dot; ascending c, strict <
        float4 c2a = *(const float4*)&c2[cbase];
        float4 c2b = *(const float4*)&c2[cbase + 4];
        float cc2[CPL] = {c2a.x, c2a.y, c2a.z, c2a.w,
                          c2b.x, c2b.y, c2b.z, c2b.w};
        #pragma unroll
        for (int p = 0; p < PW; p++) {
            float v = INFINITY; int ci = 0;
            #pragma unroll
            for (int c = 0; c < CPL; c++) {
                float s = fmaf(-2.0f, acc[p][c], cc2[c]);
                if (s < v) { v = s; ci = c; }
            }
            if (v < best[p]) { best[p] = v; bidx[p] = cbase + ci; }
        }
    }

    // cross-lane argmin per point (butterfly; all lanes converge)
    int idxs[PW];
    #pragma unroll
    for (int p = 0; p < PW; p++) {
        float v = best[p]; int i = bidx[p];
        #pragma unroll
        for (int off = 32; off; off >>= 1) {
            float v2 = __shfl_xor(v, off);
            int   i2 = __shfl_xor(i, off);
            if (v2 < v || (v2 == v && i2 < i)) { v = v2; i = i2; }
        }
        idxs[p] = i;
        if (lane == p) codes_f[base + p] = (float)i;
    }

    // fused STE update: lane handles dims {2*lane, 2*lane+1}
    float cacc = 0.0f;
    #pragma unroll
    for (int p = 0; p < PW; p++) {
        float2 q = *(const float2*)&cb[(size_t)idxs[p] * Dd + 2 * lane];
        float2 r = *(const float2*)&Rt[p][2 * lane];
        float t1x = q.x - r.x,  t1y = q.y - r.y;    // q - residual
        float qsx = r.x + t1x,  qsy = r.y + t1y;    // straight-through value
        float2 nr = make_float2(r.x - qsx, r.y - qsy);
        *(float2*)&resid[(size_t)(base + p) * Dd + 2 * lane] = nr;
        cacc = fmaf(t1x, t1x, cacc);
        cacc = fmaf(t1y, t1y, cacc);
    }
    #pragma unroll
    for (int off = 32; off; off >>= 1) cacc += __shfl_down(cacc, off);
    if (lane == 0) atomicAdd(commit, (double)cacc);
}

// ---------------------------------------------------------------------------
// final: out(B,D,T) = x - resid_final^T
// ---------------------------------------------------------------------------
__global__ void k_final(const float* __restrict__ x,
                        const float* __restrict__ resid,
                        float* __restrict__ outq) {
    __shared__ float tile[32][33];
    int b  = blockIdx.z;
    int t0 = blockIdx.x * 32, d0 = blockIdx.y * 32;
    int tx = threadIdx.x, ty = threadIdx.y;   // 32 x 8
    #pragma unroll
    for (int k = 0; k < 4; k++) {
        int t = t0 + ty + k * 8;
        tile[ty + k * 8][tx] = resid[((size_t)(b * Tt + t)) * Dd + d0 + tx];
    }
    __syncthreads();
    #pragma unroll
    for (int k = 0; k < 4; k++) {
        int d = d0 + ty + k * 8;
        size_t o = ((size_t)(b * Dd + d)) * Tt + t0 + tx;
        outq[o] = x[o] - tile[tx][ty + k * 8];
    }
}

// ---------------------------------------------------------------------------
// scalars: bw = n_q * log2(K) * frame_rate ; penalty = mean(commits)
// ---------------------------------------------------------------------------
__global__ void k_scalars(const double* __restrict__ commits,
                          const int* __restrict__ frame_rate,
                          float* __restrict__ outs) {
    if (threadIdx.x == 0 && blockIdx.x == 0) {
        double s = 0.0;
        #pragma unroll
        for (int q = 0; q < NQ; q++) s += commits[q];
        double per_elem = s / ((double)NQ * (double)BT * (double)Dd);
        outs[0] = (float)(NQ * 10.0 * (double)frame_rate[0]); // log2(1024)=10
        outs[1] = (float)per_elem;
    }
}

extern "C" void kernel_launch(void* const* d_in, const int* in_sizes, int n_in,
                              void* d_out, int out_size, void* d_ws, size_t ws_size,
                              hipStream_t stream) {
    const float* x  = (const float*)d_in[0];   // (B, D, T)
    const float* cb = (const float*)d_in[1];   // (NQ, K, D)
    const int*   fr = (const int*)d_in[2];     // frame_rate

    float* outq    = (float*)d_out;                       // (B,D,T) 4194304
    float* codes_f = outq + (size_t)Bsz * Dd * Tt;        // (NQ,B,T) 262144
    float* scal    = codes_f + (size_t)NQ * BT;           // bw, penalty

    char* ws = (char*)d_ws;
    float*  resid   = (float*)ws;                         // BT*D
    float*  cbT     = resid + (size_t)BT * Dd;            // NQ*D*K
    float*  c2      = cbT + (size_t)NQ * Dd * Kk;         // NQ*K
    double* commits = (double*)(c2 + (size_t)NQ * Kk);    // NQ

    dim3 tb(32, 8, 1);
    k_init<<<dim3(Tt / 32, Dd / 32, Bsz), tb, 0, stream>>>(x, resid);
    k_cbT<<<dim3(Kk / 32, Dd / 32, NQ), tb, 0, stream>>>(cb, cbT);
    k_c2<<<NQ * Kk / 4, 256, 0, stream>>>(cb, c2, commits);

    for (int q = 0; q < NQ; q++) {
        k_argmin_fused<<<BT / PW, 64, 0, stream>>>(
            resid,
            cbT + (size_t)q * Dd * Kk,
            cb  + (size_t)q * Kk * Dd,
            c2  + (size_t)q * Kk,
            codes_f + (size_t)q * BT,
            commits + q);
    }

    k_final<<<dim3(Tt / 32, Dd / 32, Bsz), tb, 0, stream>>>(x, resid, outq);
    k_scalars<<<1, 64, 0, stream>>>(commits, fr, scal);
}

// Round 6
// 1015.942 us; speedup vs baseline: 3.3775x; 1.1254x over previous
//
#include <hip/hip_runtime.h>
#include <math.h>

#define Bsz 8
#define Dd  128
#define Tt  4096
#define Kk  1024
#define NQ  8
#define BT  (Bsz*Tt)        // 32768 points
#define PW  16              // points per block (shared by 4 waves)
#define CPL 4               // codes per lane (64 lanes * 4 = 256 codes/wave)

// ---------------------------------------------------------------------------
// init: transpose x (B,D,T) -> resid (B,T,D)
// ---------------------------------------------------------------------------
__global__ void k_init(const float* __restrict__ x,
                       float* __restrict__ resid) {
    __shared__ float tile[32][33];
    int b  = blockIdx.z;
    int t0 = blockIdx.x * 32, d0 = blockIdx.y * 32;
    int tx = threadIdx.x, ty = threadIdx.y;   // 32 x 8
    #pragma unroll
    for (int k = 0; k < 4; k++) {
        int d = d0 + ty + k * 8;
        tile[ty + k * 8][tx] = x[((size_t)(b * Dd + d)) * Tt + t0 + tx];
    }
    __syncthreads();
    #pragma unroll
    for (int k = 0; k < 4; k++) {
        int t = t0 + ty + k * 8;
        resid[((size_t)(b * Tt + t)) * Dd + d0 + tx] = tile[tx][ty + k * 8];
    }
}

// ---------------------------------------------------------------------------
// cbT[q][d][k] = cb[q][k][d]  (once; reused by all stages)
// ---------------------------------------------------------------------------
__global__ void k_cbT(const float* __restrict__ cb, float* __restrict__ cbT) {
    __shared__ float tile[32][33];
    int q  = blockIdx.z;
    int k0 = blockIdx.x * 32, d0 = blockIdx.y * 32;
    int tx = threadIdx.x, ty = threadIdx.y;   // 32 x 8
    const float* src = cb  + (size_t)q * Kk * Dd;
    float*       dst = cbT + (size_t)q * Dd * Kk;
    #pragma unroll
    for (int r = 0; r < 4; r++) {
        int k = k0 + ty + r * 8;
        tile[ty + r * 8][tx] = src[(size_t)k * Dd + d0 + tx];
    }
    __syncthreads();
    #pragma unroll
    for (int r = 0; r < 4; r++) {
        int d = d0 + ty + r * 8;
        dst[(size_t)d * Kk + k0 + tx] = tile[tx][ty + r * 8];
    }
}

// ---------------------------------------------------------------------------
// c2[q][k] = sum_d cb[q][k][d]^2 ; zero commit accumulators
// ---------------------------------------------------------------------------
__global__ void k_c2(const float* __restrict__ cb,
                     float* __restrict__ c2,
                     double* __restrict__ commits) {
    int row  = blockIdx.x * 4 + (threadIdx.x >> 6);
    int lane = threadIdx.x & 63;
    const float* p = cb + (size_t)row * Dd;
    float a = p[lane], b = p[lane + 64];
    float s = a * a + b * b;
    #pragma unroll
    for (int off = 32; off; off >>= 1) s += __shfl_down(s, off);
    if (lane == 0) c2[row] = s;
    if (blockIdx.x == 0 && threadIdx.x < NQ) commits[threadIdx.x] = 0.0;
}

// ---------------------------------------------------------------------------
// Fused argmin + STE update. 256 threads = 4 waves; 16 points x 1024 codes.
// Wave w owns codes [w*256, w*256+256); lane owns 4 (acc[16][4] = 64 VGPR).
// One shared point tile (16x128) read via same-address broadcast ds_read_b64.
// Codebook columns stream coalesced from L2 (cbT[d][k]): (BT/16)*512KB
// = 1 GB/stage (~29 us at L2 ceiling) vs 54.6 us FMA stream -> overlap slack.
// No barriers in the hot loop. First-occurrence argmin: codes ascending in
// (lane c, lane, wave); strict < everywhere; cross-lane tie -> smaller code.
// ---------------------------------------------------------------------------
__global__ __launch_bounds__(256, 4) void k_argmin_fused(
        float* resid,
        const float* __restrict__ cbT,    // (D x K) this stage
        const float* __restrict__ cb,     // (K x D) this stage
        const float* __restrict__ c2,     // (K)     this stage
        float* __restrict__ codes_f,      // offset by q*BT
        double* __restrict__ commit) {
    __shared__ float Rt[PW][132];         // 8448 B, row stride 528 B
    __shared__ float redv[4][PW];
    __shared__ int   redi[4][PW];
    __shared__ int   sidx[PW];
    __shared__ float csum[4];

    int tid  = threadIdx.x;
    int w    = tid >> 6;
    int lane = tid & 63;
    int base = blockIdx.x * PW;

    // stage 16 pts x 128 dims = 512 float4 (coalesced; conflict-light)
    #pragma unroll
    for (int j = 0; j < 2; j++) {
        int f = tid + 256 * j;
        int p = f >> 5, d4 = f & 31;
        float4 v = *(const float4*)&resid[(size_t)(base + p) * Dd + d4 * 4];
        *(float4*)&Rt[p][d4 * 4] = v;
    }
    __syncthreads();

    int cbase = w * 256 + lane * CPL;     // this lane's 4 codes
    float acc[PW][CPL];
    #pragma unroll
    for (int p = 0; p < PW; p++) {
        acc[p][0] = 0.f; acc[p][1] = 0.f; acc[p][2] = 0.f; acc[p][3] = 0.f;
    }

    for (int k2 = 0; k2 < 64; k2++) {     // 2 dims per iteration
        const float* col = cbT + (size_t)(k2 * 2) * Kk + cbase;
        float4 cv0 = *(const float4*)(col);
        float4 cv1 = *(const float4*)(col + Kk);
        #pragma unroll
        for (int p = 0; p < PW; p++) {
            float2 rv = *(const float2*)&Rt[p][k2 * 2];   // broadcast b64
            acc[p][0] = fmaf(rv.x, cv0.x, acc[p][0]);
            acc[p][1] = fmaf(rv.x, cv0.y, acc[p][1]);
            acc[p][2] = fmaf(rv.x, cv0.z, acc[p][2]);
            acc[p][3] = fmaf(rv.x, cv0.w, acc[p][3]);
            acc[p][0] = fmaf(rv.y, cv1.x, acc[p][0]);
            acc[p][1] = fmaf(rv.y, cv1.y, acc[p][1]);
            acc[p][2] = fmaf(rv.y, cv1.z, acc[p][2]);
            acc[p][3] = fmaf(rv.y, cv1.w, acc[p][3]);
        }
    }

    // epilogue: score = c2 - 2*dot; per-lane min (ascending c, strict <),
    // then wave butterfly (tie -> smaller code), then cross-wave via LDS.
    float4 cc2 = *(const float4*)&c2[cbase];
    float cv2[CPL] = {cc2.x, cc2.y, cc2.z, cc2.w};
    #pragma unroll
    for (int p = 0; p < PW; p++) {
        float v = INFINITY; int ci = 0;
        #pragma unroll
        for (int c = 0; c < CPL; c++) {
            float s = fmaf(-2.0f, acc[p][c], cv2[c]);
            if (s < v) { v = s; ci = c; }
        }
        int i = cbase + ci;
        #pragma unroll
        for (int off = 32; off; off >>= 1) {
            float v2 = __shfl_xor(v, off);
            int   i2 = __shfl_xor(i, off);
            if (v2 < v || (v2 == v && i2 < i)) { v = v2; i = i2; }
        }
        if (lane == 0) { redv[w][p] = v; redi[w][p] = i; }
    }
    __syncthreads();

    // combine 4 waves (ascending code ranges -> strict < keeps first occ.)
    if (tid < PW) {
        float bv = redv[0][tid]; int bi = redi[0][tid];
        #pragma unroll
        for (int w2 = 1; w2 < 4; w2++) {
            float v = redv[w2][tid];
            if (v < bv) { bv = v; bi = redi[w2][tid]; }
        }
        sidx[tid] = bi;
        codes_f[base + tid] = (float)bi;
    }
    __syncthreads();

    // fused STE update: thread -> point tid>>4, dims [ (tid&15)*8, +8 )
    int p    = tid >> 4;
    int dbeg = (tid & 15) * 8;
    float cacc = 0.0f;
    #pragma unroll
    for (int h = 0; h < 2; h++) {
        float4 q = *(const float4*)&cb[(size_t)sidx[p] * Dd + dbeg + h * 4];
        float4 r = *(const float4*)&Rt[p][dbeg + h * 4];
        float t1x = q.x - r.x, t1y = q.y - r.y;
        float t1z = q.z - r.z, t1w = q.w - r.w;     // q - residual
        float qsx = r.x + t1x, qsy = r.y + t1y;
        float qsz = r.z + t1z, qsw = r.w + t1w;     // straight-through value
        float4 nr = make_float4(r.x - qsx, r.y - qsy, r.z - qsz, r.w - qsw);
        *(float4*)&resid[(size_t)(base + p) * Dd + dbeg + h * 4] = nr;
        cacc = fmaf(t1x, t1x, cacc);
        cacc = fmaf(t1y, t1y, cacc);
        cacc = fmaf(t1z, t1z, cacc);
        cacc = fmaf(t1w, t1w, cacc);
    }
    #pragma unroll
    for (int off = 32; off; off >>= 1) cacc += __shfl_down(cacc, off);
    if (lane == 0) csum[w] = cacc;
    __syncthreads();
    if (tid == 0)
        atomicAdd(commit, (double)(csum[0] + csum[1] + csum[2] + csum[3]));
}

// ---------------------------------------------------------------------------
// final: out(B,D,T) = x - resid_final^T
// ---------------------------------------------------------------------------
__global__ void k_final(const float* __restrict__ x,
                        const float* __restrict__ resid,
                        float* __restrict__ outq) {
    __shared__ float tile[32][33];
    int b  = blockIdx.z;
    int t0 = blockIdx.x * 32, d0 = blockIdx.y * 32;
    int tx = threadIdx.x, ty = threadIdx.y;   // 32 x 8
    #pragma unroll
    for (int k = 0; k < 4; k++) {
        int t = t0 + ty + k * 8;
        tile[ty + k * 8][tx] = resid[((size_t)(b * Tt + t)) * Dd + d0 + tx];
    }
    __syncthreads();
    #pragma unroll
    for (int k = 0; k < 4; k++) {
        int d = d0 + ty + k * 8;
        size_t o = ((size_t)(b * Dd + d)) * Tt + t0 + tx;
        outq[o] = x[o] - tile[tx][ty + k * 8];
    }
}

// ---------------------------------------------------------------------------
// scalars: bw = n_q * log2(K) * frame_rate ; penalty = mean(commits)
// ---------------------------------------------------------------------------
__global__ void k_scalars(const double* __restrict__ commits,
                          const int* __restrict__ frame_rate,
                          float* __restrict__ outs) {
    if (threadIdx.x == 0 && blockIdx.x == 0) {
        double s = 0.0;
        #pragma unroll
        for (int q = 0; q < NQ; q++) s += commits[q];
        double per_elem = s / ((double)NQ * (double)BT * (double)Dd);
        outs[0] = (float)(NQ * 10.0 * (double)frame_rate[0]); // log2(1024)=10
        outs[1] = (float)per_elem;
    }
}

extern "C" void kernel_launch(void* const* d_in, const int* in_sizes, int n_in,
                              void* d_out, int out_size, void* d_ws, size_t ws_size,
                              hipStream_t stream) {
    const float* x  = (const float*)d_in[0];   // (B, D, T)
    const float* cb = (const float*)d_in[1];   // (NQ, K, D)
    const int*   fr = (const int*)d_in[2];     // frame_rate

    float* outq    = (float*)d_out;                       // (B,D,T) 4194304
    float* codes_f = outq + (size_t)Bsz * Dd * Tt;        // (NQ,B,T) 262144
    float* scal    = codes_f + (size_t)NQ * BT;           // bw, penalty

    char* ws = (char*)d_ws;
    float*  resid   = (float*)ws;                         // BT*D
    float*  cbT     = resid + (size_t)BT * Dd;            // NQ*D*K
    float*  c2      = cbT + (size_t)NQ * Dd * Kk;         // NQ*K
    double* commits = (double*)(c2 + (size_t)NQ * Kk);    // NQ

    dim3 tb(32, 8, 1);
    k_init<<<dim3(Tt / 32, Dd / 32, Bsz), tb, 0, stream>>>(x, resid);
    k_cbT<<<dim3(Kk / 32, Dd / 32, NQ), tb, 0, stream>>>(cb, cbT);
    k_c2<<<NQ * Kk / 4, 256, 0, stream>>>(cb, c2, commits);

    for (int q = 0; q < NQ; q++) {
        k_argmin_fused<<<BT / PW, 256, 0, stream>>>(
            resid,
            cbT + (size_t)q * Dd * Kk,
            cb  + (size_t)q * Kk * Dd,
            c2  + (size_t)q * Kk,
            codes_f + (size_t)q * BT,
            commits + q);
    }

    k_final<<<dim3(Tt / 32, Dd / 32, Bsz), tb, 0, stream>>>(x, resid, outq);
    k_scalars<<<1, 64, 0, stream>>>(commits, fr, scal);
}